// Round 1
// baseline (173.061 us; speedup 1.0000x reference)
//
#include <hip/hip_runtime.h>

#define NB   1024
#define NT   256
#define BTOT 262144   // NB*NT == B

__device__ __forceinline__ float relu_(float x) { return fmaxf(x, 0.0f); }

__global__ __launch_bounds__(NT) void kp_fwd(
    const float* __restrict__ cin, const int* __restrict__ tmask,
    const float* __restrict__ w1, const float* __restrict__ b1,
    const float* __restrict__ g1, const float* __restrict__ bt1,
    const float* __restrict__ m1, const float* __restrict__ v1,
    const float* __restrict__ w2, const float* __restrict__ b2,
    const float* __restrict__ g2, const float* __restrict__ bt2,
    const float* __restrict__ m2, const float* __restrict__ v2,
    const float* __restrict__ w3, const float* __restrict__ b3,
    const float* __restrict__ g3, const float* __restrict__ bt3,
    const float* __restrict__ m3, const float* __restrict__ v3,
    const float* __restrict__ fw1, const float* __restrict__ fb1,
    const float* __restrict__ fw2, const float* __restrict__ fb2,
    float* __restrict__ xout, float* __restrict__ missout,
    float* __restrict__ partials)
{
    __shared__ float sW1[180], sB1[10], sA0[10];
    __shared__ float sW2[400], sB2[20];
    __shared__ float sW3[1200], sB3[30];
    __shared__ float sred[4][12];

    const int t = threadIdx.x;

    // Fold BN into conv weights/biases once per block.
    if (t < 10) {
        float s  = g1[t] * rsqrtf(v1[t] + 1e-5f);
        float bb = (b1[t] - m1[t]) * s + bt1[t];
        sB1[t] = bb;
        sA0[t] = relu_(bb);                 // zero-padded conv1 positions -> bias only
        for (int i = 0; i < 18; ++i) sW1[t * 18 + i] = w1[t * 18 + i] * s;
    } else if (t >= 64 && t < 84) {
        int o = t - 64;
        float s = g2[o] * rsqrtf(v2[o] + 1e-5f);
        sB2[o] = (b2[o] - m2[o]) * s + bt2[o];
        for (int i = 0; i < 20; ++i) sW2[o * 20 + i] = w2[o * 20 + i] * s;
    } else if (t >= 128 && t < 158) {
        int o = t - 128;
        float s = g3[o] * rsqrtf(v3[o] + 1e-5f);
        sB3[o] = (b3[o] - m3[o]) * s + bt3[o];
        for (int i = 0; i < 40; ++i) sW3[o * 40 + i] = w3[o * 40 + i] * s;
    }
    __syncthreads();

    const int tid = blockIdx.x * NT + t;
    const float* cp = cin + (size_t)tid * 36;

    float c[36];
    #pragma unroll
    for (int i = 0; i < 9; ++i)
        *(float4*)(c + 4 * i) = *(const float4*)(cp + 4 * i);

    // miss_mask output (c != -1), written early while c is live
    {
        float* mo = missout + (size_t)tid * 36;
        #pragma unroll
        for (int k = 0; k < 36; ++k) mo[k] = (c[k] != -1.0f) ? 1.0f : 0.0f;
    }

    // conv1 (K=1, pad=1): only positions 1,2 see data; 0,3 are the folded constant
    float a1[10][3];
    #pragma unroll
    for (int o = 0; o < 10; ++o) {
        float acc0 = sB1[o], acc1 = sB1[o];
        #pragma unroll
        for (int i = 0; i < 18; ++i) {
            float w = sW1[o * 18 + i];
            acc0 += w * c[2 * i];
            acc1 += w * c[2 * i + 1];
        }
        a1[o][0] = sA0[o];          // pos 0 (== pos 3)
        a1[o][1] = relu_(acc0);     // pos 1
        a1[o][2] = relu_(acc1);     // pos 2
    }

    // conv2 (K=2, pad=0): len 4 -> 3
    float a2[20][3];
    #pragma unroll
    for (int o = 0; o < 20; ++o) {
        float t0 = sB2[o], t1 = sB2[o], t2 = sB2[o];
        #pragma unroll
        for (int i = 0; i < 10; ++i) {
            float wa = sW2[o * 20 + i * 2];
            float wb = sW2[o * 20 + i * 2 + 1];
            float p0 = a1[i][0], p1 = a1[i][1], p2 = a1[i][2];
            t0 += p0 * wa + p1 * wb;
            t1 += p1 * wa + p2 * wb;
            t2 += p2 * wa + p0 * wb;   // pos3 == pos0
        }
        a2[o][0] = relu_(t0);
        a2[o][1] = relu_(t1);
        a2[o][2] = relu_(t2);
    }

    // conv3 (K=2, pad=0): len 3 -> 2, flatten [30,2] -> f[60]
    float f[60];
    #pragma unroll
    for (int o = 0; o < 30; ++o) {
        float t0 = sB3[o], t1 = sB3[o];
        #pragma unroll
        for (int i = 0; i < 20; ++i) {
            float wa = sW3[o * 40 + i * 2];
            float wb = sW3[o * 40 + i * 2 + 1];
            t0 += a2[i][0] * wa + a2[i][1] * wb;
            t1 += a2[i][1] * wa + a2[i][2] * wb;
        }
        f[2 * o]     = relu_(t0);
        f[2 * o + 1] = relu_(t1);
    }

    // fc1 (relu) fused with fc2: z_j consumed immediately (no z[100] in regs)
    float ov[36];
    #pragma unroll
    for (int n = 0; n < 36; ++n) ov[n] = fb2[n];
    for (int j = 0; j < 100; ++j) {
        float acc = fb1[j];
        #pragma unroll
        for (int k = 0; k < 60; ++k) acc += f[k] * fw1[j * 60 + k];
        float z = relu_(acc);
        #pragma unroll
        for (int n = 0; n < 36; ++n) ov[n] += z * fw2[n * 100 + j];
    }

    // store x
    {
        float* xp = xout + (size_t)tid * 36;
        #pragma unroll
        for (int i = 0; i < 9; ++i)
            *(float4*)(xp + 4 * i) = *(float4*)(ov + 4 * i);
    }

    // ---- losses: reload c (L2/L3-resident), keep peak VGPR down ----
    float cg[36];
    #pragma unroll
    for (int i = 0; i < 9; ++i)
        *(float4*)(cg + 4 * i) = *(const float4*)(cp + 4 * i);

    float s1 = 0.f, s2 = 0.f;   // kp_loss numerator / denominator
    {
        const int* mp = tmask + (size_t)tid * 36;
        #pragma unroll
        for (int i = 0; i < 9; ++i) {
            int4 mv = *(const int4*)(mp + 4 * i);
            int mm0 = mv.x, mm1 = mv.y, mm2 = mv.z, mm3 = mv.w;
            int k = 4 * i;
            float d0 = ov[k+0] - cg[k+0], m0 = (float)mm0;
            float d1 = ov[k+1] - cg[k+1], m1_ = (float)mm1;
            float d2 = ov[k+2] - cg[k+2], m2_ = (float)mm2;
            float d3 = ov[k+3] - cg[k+3], m3_ = (float)mm3;
            s1 += d0*d0*m0 + d1*d1*m1_ + d2*d2*m2_ + d3*d3*m3_;
            s2 += m0 + m1_ + m2_ + m3_;
        }
    }

    float sp[5], np[5];
    {
        // head: (0,14,15); faithful to ref: gt mixes x[:,15,0] and c[:,15,1]
        float dxa = ov[0] - ov[28], dya = ov[1] - ov[29];
        float dxb = ov[0] - ov[30], dyb = ov[1] - ov[31];
        float pred = 0.5f * (sqrtf(dxa*dxa + dya*dya) + sqrtf(dxb*dxb + dyb*dyb));
        float cxa = cg[0] - cg[28], cya = cg[1] - cg[29];
        float gxa = cg[0] - ov[30], gya = cg[1] - cg[31];
        float gt = 0.5f * (sqrtf(cxa*cxa + cya*cya) + sqrtf(gxa*gxa + gya*gya));
        float vf = (cg[0] != -1.f && cg[28] != -1.f && cg[30] != -1.f) ? 1.f : 0.f;
        float e = pred - gt;
        sp[0] = e * e * vf; np[0] = vf;
    }
    #pragma unroll
    for (int p = 0; p < 4; ++p) {
        const int a = 2 + 3 * p, b = a + 1, cc = a + 2;
        float dxa = ov[2*a] - ov[2*b],  dya = ov[2*a+1] - ov[2*b+1];
        float dxb = ov[2*b] - ov[2*cc], dyb = ov[2*b+1] - ov[2*cc+1];
        float pred = 0.5f * (sqrtf(dxa*dxa + dya*dya) + sqrtf(dxb*dxb + dyb*dyb));
        float cxa = cg[2*a] - cg[2*b], cya = cg[2*a+1] - cg[2*b+1];
        float gxa = cg[2*b] - ov[2*cc], gya = cg[2*b+1] - cg[2*cc+1];
        float gt = 0.5f * (sqrtf(cxa*cxa + cya*cya) + sqrtf(gxa*gxa + gya*gya));
        float vf = (cg[2*a] != -1.f && cg[2*b] != -1.f && cg[2*cc] != -1.f) ? 1.f : 0.f;
        float e = pred - gt;
        sp[p + 1] = e * e * vf; np[p + 1] = vf;
    }

    // ---- block reduction of 12 scalars ----
    float rv[12] = { s1, s2, sp[0], np[0], sp[1], np[1],
                     sp[2], np[2], sp[3], np[3], sp[4], np[4] };
    #pragma unroll
    for (int v = 0; v < 12; ++v) {
        #pragma unroll
        for (int off = 32; off > 0; off >>= 1)
            rv[v] += __shfl_down(rv[v], off, 64);
    }
    const int wave = t >> 6, lane = t & 63;
    if (lane == 0) {
        #pragma unroll
        for (int v = 0; v < 12; ++v) sred[wave][v] = rv[v];
    }
    __syncthreads();
    if (t < 12) {
        float s = sred[0][t] + sred[1][t] + sred[2][t] + sred[3][t];
        partials[blockIdx.x * 12 + t] = s;
    }
}

__global__ __launch_bounds__(256) void kp_fin(const float* __restrict__ partials,
                                              float* __restrict__ total_out)
{
    __shared__ float sred[4][12];
    const int t = threadIdx.x;
    float rv[12];
    #pragma unroll
    for (int v = 0; v < 12; ++v) rv[v] = 0.f;
    for (int b = t; b < NB; b += 256) {
        #pragma unroll
        for (int v = 0; v < 12; ++v) rv[v] += partials[b * 12 + v];
    }
    #pragma unroll
    for (int v = 0; v < 12; ++v) {
        #pragma unroll
        for (int off = 32; off > 0; off >>= 1)
            rv[v] += __shfl_down(rv[v], off, 64);
    }
    const int wave = t >> 6, lane = t & 63;
    if (lane == 0) {
        #pragma unroll
        for (int v = 0; v < 12; ++v) sred[wave][v] = rv[v];
    }
    __syncthreads();
    if (t == 0) {
        float acc[12];
        #pragma unroll
        for (int v = 0; v < 12; ++v)
            acc[v] = sred[0][v] + sred[1][v] + sred[2][v] + sred[3][v];
        float total = acc[0] / acc[1];   // kp_loss = S1 / sum(mask)
        #pragma unroll
        for (int p = 0; p < 5; ++p) {
            float s = acc[2 + 2 * p], n = acc[3 + 2 * p];
            total += (n > 0.f) ? (s / fmaxf(n, 1.f)) : 0.f;
        }
        total_out[0] = total;
    }
}

extern "C" void kernel_launch(void* const* d_in, const int* in_sizes, int n_in,
                              void* d_out, int out_size, void* d_ws, size_t ws_size,
                              hipStream_t stream)
{
    const float* cin   = (const float*)d_in[0];
    const int*   tmask = (const int*)  d_in[1];
    const float* w1  = (const float*)d_in[2];
    const float* b1  = (const float*)d_in[3];
    const float* g1  = (const float*)d_in[4];
    const float* bt1 = (const float*)d_in[5];
    const float* m1  = (const float*)d_in[6];
    const float* v1  = (const float*)d_in[7];
    const float* w2  = (const float*)d_in[8];
    const float* b2  = (const float*)d_in[9];
    const float* g2  = (const float*)d_in[10];
    const float* bt2 = (const float*)d_in[11];
    const float* m2  = (const float*)d_in[12];
    const float* v2  = (const float*)d_in[13];
    const float* w3  = (const float*)d_in[14];
    const float* b3  = (const float*)d_in[15];
    const float* g3  = (const float*)d_in[16];
    const float* bt3 = (const float*)d_in[17];
    const float* m3  = (const float*)d_in[18];
    const float* v3  = (const float*)d_in[19];
    const float* fw1 = (const float*)d_in[20];
    const float* fb1 = (const float*)d_in[21];
    const float* fw2 = (const float*)d_in[22];
    const float* fb2 = (const float*)d_in[23];

    float* xout     = (float*)d_out;                       // [B,36]
    float* total    = (float*)d_out + (size_t)BTOT * 36;   // scalar
    float* missout  = total + 1;                           // [B,36] as f32 0/1
    float* partials = (float*)d_ws;                        // [NB,12]

    kp_fwd<<<NB, NT, 0, stream>>>(cin, tmask,
        w1, b1, g1, bt1, m1, v1,
        w2, b2, g2, bt2, m2, v2,
        w3, b3, g3, bt3, m3, v3,
        fw1, fb1, fw2, fb2,
        xout, missout, partials);

    kp_fin<<<1, 256, 0, stream>>>(partials, total);
}

// Round 2
// 169.900 us; speedup vs baseline: 1.0186x; 1.0186x over previous
//
#include <hip/hip_runtime.h>

#define NB   1024
#define NT   256
#define BTOT 262144   // NB*NT == B

__device__ __forceinline__ float relu_(float x) { return fmaxf(x, 0.0f); }

__global__ __launch_bounds__(NT) void kp_fwd(
    const float* __restrict__ cin, const int* __restrict__ tmask,
    const float* __restrict__ w1, const float* __restrict__ b1,
    const float* __restrict__ g1, const float* __restrict__ bt1,
    const float* __restrict__ m1, const float* __restrict__ v1,
    const float* __restrict__ w2, const float* __restrict__ b2,
    const float* __restrict__ g2, const float* __restrict__ bt2,
    const float* __restrict__ m2, const float* __restrict__ v2,
    const float* __restrict__ w3, const float* __restrict__ b3,
    const float* __restrict__ g3, const float* __restrict__ bt3,
    const float* __restrict__ m3, const float* __restrict__ v3,
    const float* __restrict__ fw1, const float* __restrict__ fb1,
    const float* __restrict__ fw2, const float* __restrict__ fb2,
    float* __restrict__ xout, float* __restrict__ missout,
    float* __restrict__ partials)
{
    // tile stride 37 (odd): row reads hit all 32 banks, 2 lanes/bank = free
    __shared__ float tile[NT * 37];
    __shared__ float sW1[180], sB1[10], sA0[10];
    __shared__ float sW2[400], sB2[20];
    __shared__ float sW3[1200], sB3[30];
    __shared__ float sred[4][12];

    const int t = threadIdx.x;

    // Fold BN into conv weights/biases once per block.
    if (t < 10) {
        float s  = g1[t] * rsqrtf(v1[t] + 1e-5f);
        float bb = (b1[t] - m1[t]) * s + bt1[t];
        sB1[t] = bb;
        sA0[t] = relu_(bb);                 // zero-padded conv1 positions -> bias only
        for (int i = 0; i < 18; ++i) sW1[t * 18 + i] = w1[t * 18 + i] * s;
    } else if (t >= 64 && t < 84) {
        int o = t - 64;
        float s = g2[o] * rsqrtf(v2[o] + 1e-5f);
        sB2[o] = (b2[o] - m2[o]) * s + bt2[o];
        for (int i = 0; i < 20; ++i) sW2[o * 20 + i] = w2[o * 20 + i] * s;
    } else if (t >= 128 && t < 158) {
        int o = t - 128;
        float s = g3[o] * rsqrtf(v3[o] + 1e-5f);
        sB3[o] = (b3[o] - m3[o]) * s + bt3[o];
        for (int i = 0; i < 40; ++i) sW3[o * 40 + i] = w3[o * 40 + i] * s;
    }

    const size_t blkBase = (size_t)blockIdx.x * (NT * 36);
    const float4* cin4 = (const float4*)(cin + blkBase);
    const int4*   tm4  = (const int4*)(tmask + blkBase);
    float4*       x4   = (float4*)(xout + blkBase);
    float*        mo   = missout + blkBase;

    // ---- Phase A: coalesced input load -> LDS transpose scatter ----
    #pragma unroll
    for (int i = 0; i < 9; ++i) {
        int g4 = i * NT + t;                 // float4 chunk index in block region
        float4 v = cin4[g4];
        unsigned g = 4u * (unsigned)g4;      // flat float index (0..9215)
        unsigned row = g / 36u;
        unsigned col = g - row * 36u;        // 36%4==0 -> chunk never straddles rows
        float* tp = &tile[row * 37u + col];
        tp[0] = v.x; tp[1] = v.y; tp[2] = v.z; tp[3] = v.w;
    }
    __syncthreads();   // covers weight fold + tile scatter

    // ---- Phase B: per-sample compute from own LDS row (conflict-free) ----
    float c[36];
    {
        const float* myrow = &tile[t * 37];
        #pragma unroll
        for (int k = 0; k < 36; ++k) c[k] = myrow[k];
    }

    // retain only the gt-side scalars of the 5 part losses (pure-c pieces)
    float pd1[5], pbx[5], pgy[5], pvf[5];
    {   // head: (a=0, b=14, cc=15); gt mixes ov[30] later
        float dx = c[0] - c[28], dy = c[1] - c[29];
        pd1[0] = sqrtf(dx * dx + dy * dy);
        pbx[0] = c[0];
        pgy[0] = c[1] - c[31];
        pvf[0] = (c[0] != -1.f && c[28] != -1.f && c[30] != -1.f) ? 1.f : 0.f;
    }
    #pragma unroll
    for (int p = 0; p < 4; ++p) {
        const int a = 2 + 3 * p, b = a + 1, cc = a + 2;
        float dx = c[2 * a] - c[2 * b], dy = c[2 * a + 1] - c[2 * b + 1];
        pd1[p + 1] = sqrtf(dx * dx + dy * dy);
        pbx[p + 1] = c[2 * b];
        pgy[p + 1] = c[2 * b + 1] - c[2 * cc + 1];
        pvf[p + 1] = (c[2 * a] != -1.f && c[2 * b] != -1.f && c[2 * cc] != -1.f) ? 1.f : 0.f;
    }

    // conv1 (K=1, pad=1): only positions 1,2 see data; 0,3 are the folded constant
    float a1[10][3];
    #pragma unroll
    for (int o = 0; o < 10; ++o) {
        float acc0 = sB1[o], acc1 = sB1[o];
        #pragma unroll
        for (int i = 0; i < 18; ++i) {
            float w = sW1[o * 18 + i];
            acc0 += w * c[2 * i];
            acc1 += w * c[2 * i + 1];
        }
        a1[o][0] = sA0[o];
        a1[o][1] = relu_(acc0);
        a1[o][2] = relu_(acc1);
    }

    // conv2 (K=2, pad=0): len 4 -> 3
    float a2[20][3];
    #pragma unroll
    for (int o = 0; o < 20; ++o) {
        float t0 = sB2[o], t1 = sB2[o], t2 = sB2[o];
        #pragma unroll
        for (int i = 0; i < 10; ++i) {
            float wa = sW2[o * 20 + i * 2];
            float wb = sW2[o * 20 + i * 2 + 1];
            float p0 = a1[i][0], p1 = a1[i][1], p2 = a1[i][2];
            t0 += p0 * wa + p1 * wb;
            t1 += p1 * wa + p2 * wb;
            t2 += p2 * wa + p0 * wb;   // pos3 == pos0
        }
        a2[o][0] = relu_(t0);
        a2[o][1] = relu_(t1);
        a2[o][2] = relu_(t2);
    }

    // conv3 (K=2, pad=0): len 3 -> 2, flatten [30,2] -> f[60]
    float f[60];
    #pragma unroll
    for (int o = 0; o < 30; ++o) {
        float t0 = sB3[o], t1 = sB3[o];
        #pragma unroll
        for (int i = 0; i < 20; ++i) {
            float wa = sW3[o * 40 + i * 2];
            float wb = sW3[o * 40 + i * 2 + 1];
            t0 += a2[i][0] * wa + a2[i][1] * wb;
            t1 += a2[i][1] * wa + a2[i][2] * wb;
        }
        f[2 * o]     = relu_(t0);
        f[2 * o + 1] = relu_(t1);
    }

    // fc1 (relu) fused with fc2
    float ov[36];
    #pragma unroll
    for (int n = 0; n < 36; ++n) ov[n] = fb2[n];
    for (int j = 0; j < 100; ++j) {
        float acc = fb1[j];
        #pragma unroll
        for (int k = 0; k < 60; ++k) acc += f[k] * fw1[j * 60 + k];
        float z = relu_(acc);
        #pragma unroll
        for (int n = 0; n < 36; ++n) ov[n] += z * fw2[n * 100 + j];
    }

    // part losses (pred from ov; gt finished with retained scalars)
    float sp[5], np[5];
    {   // head: pred = (dist(x0,x14)+dist(x0,x15))/2
        float dxa = ov[0] - ov[28], dya = ov[1] - ov[29];
        float dxb = ov[0] - ov[30], dyb = ov[1] - ov[31];
        float pred = 0.5f * (sqrtf(dxa*dxa + dya*dya) + sqrtf(dxb*dxb + dyb*dyb));
        float gxa = pbx[0] - ov[30];
        float gt = 0.5f * (pd1[0] + sqrtf(gxa * gxa + pgy[0] * pgy[0]));
        float e = pred - gt;
        sp[0] = e * e * pvf[0]; np[0] = pvf[0];
    }
    #pragma unroll
    for (int p = 0; p < 4; ++p) {
        const int a = 2 + 3 * p, b = a + 1, cc = a + 2;
        float dxa = ov[2*a] - ov[2*b],  dya = ov[2*a+1] - ov[2*b+1];
        float dxb = ov[2*b] - ov[2*cc], dyb = ov[2*b+1] - ov[2*cc+1];
        float pred = 0.5f * (sqrtf(dxa*dxa + dya*dya) + sqrtf(dxb*dxb + dyb*dyb));
        float gxa = pbx[p + 1] - ov[2 * cc];
        float gt = 0.5f * (pd1[p + 1] + sqrtf(gxa * gxa + pgy[p + 1] * pgy[p + 1]));
        float e = pred - gt;
        sp[p + 1] = e * e * pvf[p + 1]; np[p + 1] = pvf[p + 1];
    }

    // ---- Phase C: ov -> own LDS row (no barrier needed: row t touched only by thread t)
    {
        float* myrow = &tile[t * 37];
        #pragma unroll
        for (int k = 0; k < 36; ++k) myrow[k] = ov[k];
    }
    __syncthreads();

    // coalesced x store + miss store + elementwise kp-loss
    float s1 = 0.f, s2 = 0.f;
    #pragma unroll
    for (int i = 0; i < 9; ++i) {
        int g4 = i * NT + t;
        unsigned g = 4u * (unsigned)g4;
        unsigned row = g / 36u;
        unsigned col = g - row * 36u;
        const float* tp = &tile[row * 37u + col];
        float4 xv; xv.x = tp[0]; xv.y = tp[1]; xv.z = tp[2]; xv.w = tp[3];
        float4 cv = cin4[g4];     // L2-hot second read
        int4   m  = tm4[g4];
        x4[g4] = xv;
        // miss base is 4B-aligned only (odd float offset) -> dword stores
        mo[g + 0] = (cv.x != -1.f) ? 1.f : 0.f;
        mo[g + 1] = (cv.y != -1.f) ? 1.f : 0.f;
        mo[g + 2] = (cv.z != -1.f) ? 1.f : 0.f;
        mo[g + 3] = (cv.w != -1.f) ? 1.f : 0.f;
        float m0 = (float)m.x, m1_ = (float)m.y, m2_ = (float)m.z, m3_ = (float)m.w;
        float d0 = xv.x - cv.x, d1 = xv.y - cv.y, d2 = xv.z - cv.z, d3 = xv.w - cv.w;
        s1 += d0*d0*m0 + d1*d1*m1_ + d2*d2*m2_ + d3*d3*m3_;
        s2 += m0 + m1_ + m2_ + m3_;
    }

    // ---- block reduction of 12 scalars ----
    float rv[12] = { s1, s2, sp[0], np[0], sp[1], np[1],
                     sp[2], np[2], sp[3], np[3], sp[4], np[4] };
    #pragma unroll
    for (int v = 0; v < 12; ++v) {
        #pragma unroll
        for (int off = 32; off > 0; off >>= 1)
            rv[v] += __shfl_down(rv[v], off, 64);
    }
    const int wave = t >> 6, lane = t & 63;
    if (lane == 0) {
        #pragma unroll
        for (int v = 0; v < 12; ++v) sred[wave][v] = rv[v];
    }
    __syncthreads();
    if (t < 12) {
        float s = sred[0][t] + sred[1][t] + sred[2][t] + sred[3][t];
        partials[blockIdx.x * 12 + t] = s;
    }
}

__global__ __launch_bounds__(256) void kp_fin(const float* __restrict__ partials,
                                              float* __restrict__ total_out)
{
    __shared__ float sred[4][12];
    const int t = threadIdx.x;
    float rv[12];
    #pragma unroll
    for (int v = 0; v < 12; ++v) rv[v] = 0.f;
    for (int b = t; b < NB; b += 256) {
        #pragma unroll
        for (int v = 0; v < 12; ++v) rv[v] += partials[b * 12 + v];
    }
    #pragma unroll
    for (int v = 0; v < 12; ++v) {
        #pragma unroll
        for (int off = 32; off > 0; off >>= 1)
            rv[v] += __shfl_down(rv[v], off, 64);
    }
    const int wave = t >> 6, lane = t & 63;
    if (lane == 0) {
        #pragma unroll
        for (int v = 0; v < 12; ++v) sred[wave][v] = rv[v];
    }
    __syncthreads();
    if (t == 0) {
        float acc[12];
        #pragma unroll
        for (int v = 0; v < 12; ++v)
            acc[v] = sred[0][v] + sred[1][v] + sred[2][v] + sred[3][v];
        float total = acc[0] / acc[1];   // kp_loss = S1 / sum(mask)
        #pragma unroll
        for (int p = 0; p < 5; ++p) {
            float s = acc[2 + 2 * p], n = acc[3 + 2 * p];
            total += (n > 0.f) ? (s / fmaxf(n, 1.f)) : 0.f;
        }
        total_out[0] = total;
    }
}

extern "C" void kernel_launch(void* const* d_in, const int* in_sizes, int n_in,
                              void* d_out, int out_size, void* d_ws, size_t ws_size,
                              hipStream_t stream)
{
    const float* cin   = (const float*)d_in[0];
    const int*   tmask = (const int*)  d_in[1];
    const float* w1  = (const float*)d_in[2];
    const float* b1  = (const float*)d_in[3];
    const float* g1  = (const float*)d_in[4];
    const float* bt1 = (const float*)d_in[5];
    const float* m1  = (const float*)d_in[6];
    const float* v1  = (const float*)d_in[7];
    const float* w2  = (const float*)d_in[8];
    const float* b2  = (const float*)d_in[9];
    const float* g2  = (const float*)d_in[10];
    const float* bt2 = (const float*)d_in[11];
    const float* m2  = (const float*)d_in[12];
    const float* v2  = (const float*)d_in[13];
    const float* w3  = (const float*)d_in[14];
    const float* b3  = (const float*)d_in[15];
    const float* g3  = (const float*)d_in[16];
    const float* bt3 = (const float*)d_in[17];
    const float* m3  = (const float*)d_in[18];
    const float* v3  = (const float*)d_in[19];
    const float* fw1 = (const float*)d_in[20];
    const float* fb1 = (const float*)d_in[21];
    const float* fw2 = (const float*)d_in[22];
    const float* fb2 = (const float*)d_in[23];

    float* xout     = (float*)d_out;                       // [B,36]
    float* total    = (float*)d_out + (size_t)BTOT * 36;   // scalar
    float* missout  = total + 1;                           // [B,36] as f32 0/1
    float* partials = (float*)d_ws;                        // [NB,12]

    kp_fwd<<<NB, NT, 0, stream>>>(cin, tmask,
        w1, b1, g1, bt1, m1, v1,
        w2, b2, g2, bt2, m2, v2,
        w3, b3, g3, bt3, m3, v3,
        fw1, fb1, fw2, fb2,
        xout, missout, partials);

    kp_fin<<<1, 256, 0, stream>>>(partials, total);
}

// Round 3
// 110.195 us; speedup vs baseline: 1.5705x; 1.5418x over previous
//
#include <hip/hip_runtime.h>

#define NB   1024
#define NT   256
#define BTOT 262144   // NB*NT == B

typedef __attribute__((ext_vector_type(8))) short short8;
typedef __attribute__((ext_vector_type(4))) float f32x4;

__device__ __forceinline__ float relu_(float x) { return fmaxf(x, 0.0f); }

__device__ __forceinline__ short f2bf(float x) {   // RNE f32->bf16
    unsigned u = __float_as_uint(x);
    unsigned r = (u + 0x7FFFu + ((u >> 16) & 1u)) >> 16;
    return (short)r;
}

// 160B rows, XOR-swizzle the 16B-block index with row&7 (blocks 0..7 only;
// block 8 (bytes 128..143) stays linear).
__device__ __forceinline__ unsigned swz(unsigned row, unsigned byteoff) {
    unsigned blk = byteoff >> 4, rest = byteoff & 15u;
    if (blk < 8u) blk ^= (row & 7u);
    return row * 160u + blk * 16u + rest;
}

__global__ __launch_bounds__(NT) void kp_fwd(
    const float* __restrict__ cin, const int* __restrict__ tmask,
    const float* __restrict__ w1, const float* __restrict__ b1,
    const float* __restrict__ g1, const float* __restrict__ bt1,
    const float* __restrict__ m1, const float* __restrict__ v1,
    const float* __restrict__ w2, const float* __restrict__ b2,
    const float* __restrict__ g2, const float* __restrict__ bt2,
    const float* __restrict__ m2, const float* __restrict__ v2,
    const float* __restrict__ w3, const float* __restrict__ b3,
    const float* __restrict__ g3, const float* __restrict__ bt3,
    const float* __restrict__ m3, const float* __restrict__ v3,
    const float* __restrict__ fw1, const float* __restrict__ fb1,
    const float* __restrict__ fw2, const float* __restrict__ fb2,
    float* __restrict__ xout, float* __restrict__ missout,
    float* __restrict__ partials)
{
    __shared__ __align__(16) unsigned char sAB[NT * 160];   // 40KB row buffer
    __shared__ __align__(16) short sB1f[14 * 512];          // fc1 B-frags [n*2+kt][lane][8]
    __shared__ __align__(16) short sB2f[12 * 512];          // fc2 B-frags [n*4+kt][lane][8]
    __shared__ float sW1[180], sB1[10], sA0[10];
    __shared__ float sW2[400], sB2c[20];
    __shared__ float sW3[1200], sB3c[30];
    __shared__ float sred[4][12];

    const int t = threadIdx.x;

    // ---- Phase 0: fold BN into conv weights; build bf16 FC B-fragments ----
    if (t < 10) {
        float s  = g1[t] * rsqrtf(v1[t] + 1e-5f);
        float bb = (b1[t] - m1[t]) * s + bt1[t];
        sB1[t] = bb;
        sA0[t] = relu_(bb);
        for (int i = 0; i < 18; ++i) sW1[t * 18 + i] = w1[t * 18 + i] * s;
    } else if (t >= 64 && t < 84) {
        int o = t - 64;
        float s = g2[o] * rsqrtf(v2[o] + 1e-5f);
        sB2c[o] = (b2[o] - m2[o]) * s + bt2[o];
        for (int i = 0; i < 20; ++i) sW2[o * 20 + i] = w2[o * 20 + i] * s;
    } else if (t >= 128 && t < 158) {
        int o = t - 128;
        float s = g3[o] * rsqrtf(v3[o] + 1e-5f);
        sB3c[o] = (b3[o] - m3[o]) * s + bt3[o];
        for (int i = 0; i < 40; ++i) sW3[o * 40 + i] = w3[o * 40 + i] * s;
    }
    // fc1 B-frag fill: B1[k][j] = fw1[j*60+k], j<100 & k<60 else 0
    for (int e = t; e < 14 * 512; e += NT) {
        int pos = e >> 9, l = (e >> 3) & 63, j = e & 7;
        int n = pos >> 1, kt = pos & 1;
        int col = 16 * n + (l & 15);
        int k   = kt * 32 + (l >> 4) * 8 + j;
        float v = (col < 100 && k < 60) ? fw1[col * 60 + k] : 0.f;
        sB1f[e] = f2bf(v);
    }
    // fc2 B-frag fill: B2[k][cc] = fw2[cc*100+k], cc<36 & k<100 else 0
    for (int e = t; e < 12 * 512; e += NT) {
        int pos = e >> 9, l = (e >> 3) & 63, j = e & 7;
        int n = pos >> 2, kt = pos & 3;
        int col = 16 * n + (l & 15);
        int k   = kt * 32 + (l >> 4) * 8 + j;
        float v = (col < 36 && k < 100) ? fw2[col * 100 + k] : 0.f;
        sB2f[e] = f2bf(v);
    }
    __syncthreads();

    const int tid = blockIdx.x * NT + t;
    const float* cp = cin + (size_t)tid * 36;

    float c[36];
    #pragma unroll
    for (int i = 0; i < 9; ++i)
        *(float4*)(c + 4 * i) = *(const float4*)(cp + 4 * i);

    // retained gt-side scalars for the 5 part losses
    float pd1[5], pbx[5], pgy[5], pvf[5];
    {
        float dx = c[0] - c[28], dy = c[1] - c[29];
        pd1[0] = sqrtf(dx * dx + dy * dy);
        pbx[0] = c[0];
        pgy[0] = c[1] - c[31];
        pvf[0] = (c[0] != -1.f && c[28] != -1.f && c[30] != -1.f) ? 1.f : 0.f;
    }
    #pragma unroll
    for (int p = 0; p < 4; ++p) {
        const int a = 2 + 3 * p, b = a + 1, cc = a + 2;
        float dx = c[2 * a] - c[2 * b], dy = c[2 * a + 1] - c[2 * b + 1];
        pd1[p + 1] = sqrtf(dx * dx + dy * dy);
        pbx[p + 1] = c[2 * b];
        pgy[p + 1] = c[2 * b + 1] - c[2 * cc + 1];
        pvf[p + 1] = (c[2 * a] != -1.f && c[2 * b] != -1.f && c[2 * cc] != -1.f) ? 1.f : 0.f;
    }

    // ---- convs on VALU (per-thread) ----
    float a1[10][3];
    #pragma unroll
    for (int o = 0; o < 10; ++o) {
        float acc0 = sB1[o], acc1 = sB1[o];
        #pragma unroll
        for (int i = 0; i < 18; ++i) {
            float w = sW1[o * 18 + i];
            acc0 += w * c[2 * i];
            acc1 += w * c[2 * i + 1];
        }
        a1[o][0] = sA0[o];
        a1[o][1] = relu_(acc0);
        a1[o][2] = relu_(acc1);
    }
    float a2[20][3];
    #pragma unroll
    for (int o = 0; o < 20; ++o) {
        float t0 = sB2c[o], t1 = sB2c[o], t2 = sB2c[o];
        #pragma unroll
        for (int i = 0; i < 10; ++i) {
            float wa = sW2[o * 20 + i * 2];
            float wb = sW2[o * 20 + i * 2 + 1];
            float p0 = a1[i][0], p1 = a1[i][1], p2 = a1[i][2];
            t0 += p0 * wa + p1 * wb;
            t1 += p1 * wa + p2 * wb;
            t2 += p2 * wa + p0 * wb;
        }
        a2[o][0] = relu_(t0);
        a2[o][1] = relu_(t1);
        a2[o][2] = relu_(t2);
    }
    float f[60];
    #pragma unroll
    for (int o = 0; o < 30; ++o) {
        float t0 = sB3c[o], t1 = sB3c[o];
        #pragma unroll
        for (int i = 0; i < 20; ++i) {
            float wa = sW3[o * 40 + i * 2];
            float wb = sW3[o * 40 + i * 2 + 1];
            t0 += a2[i][0] * wa + a2[i][1] * wb;
            t1 += a2[i][1] * wa + a2[i][2] * wb;
        }
        f[2 * o]     = relu_(t0);
        f[2 * o + 1] = relu_(t1);
    }

    // ---- f -> own LDS row as bf16 (cols 60..63 zero) ----
    #pragma unroll
    for (int b = 0; b < 8; ++b) {
        short8 pk;
        #pragma unroll
        for (int j = 0; j < 8; ++j) {
            int idx = b * 8 + j;
            pk[j] = (idx < 60) ? f2bf(f[idx]) : (short)0;
        }
        *(short8*)&sAB[swz((unsigned)t, (unsigned)(b * 16))] = pk;
    }

    // ---- MFMA FC section (wave-private rows; in-order DS => no barriers) ----
    const int lane = t & 63;
    const unsigned wbase = (unsigned)(t & ~63);
    const unsigned lrow  = (unsigned)(lane & 15);
    const unsigned lkg   = (unsigned)(lane >> 4);   // 0..3

    float fb1v[7], fb2v[3];
    #pragma unroll
    for (int n = 0; n < 7; ++n) { int j = 16 * n + (int)lrow; fb1v[n] = (j < 100) ? fb1[j] : 0.f; }
    #pragma unroll
    for (int n = 0; n < 3; ++n) { int cc = 16 * n + (int)lrow; fb2v[n] = (cc < 36) ? fb2[cc] : 0.f; }

    #pragma unroll 1
    for (int m = 0; m < 4; ++m) {
        const unsigned Rbase = wbase + 16u * (unsigned)m;
        const unsigned myrow = Rbase + lrow;

        short8 A1a = *(const short8*)&sAB[swz(myrow, lkg * 16u)];
        short8 A1b = *(const short8*)&sAB[swz(myrow, 64u + lkg * 16u)];

        f32x4 acc1[7];
        #pragma unroll
        for (int n = 0; n < 7; ++n) acc1[n] = (f32x4){0.f, 0.f, 0.f, 0.f};
        #pragma unroll
        for (int n = 0; n < 7; ++n) {
            short8 b0 = *(const short8*)&sB1f[((n * 2 + 0) * 64 + lane) * 8];
            acc1[n] = __builtin_amdgcn_mfma_f32_16x16x32_bf16(A1a, b0, acc1[n], 0, 0, 0);
            short8 b1 = *(const short8*)&sB1f[((n * 2 + 1) * 64 + lane) * 8];
            acc1[n] = __builtin_amdgcn_mfma_f32_16x16x32_bf16(A1b, b1, acc1[n], 0, 0, 0);
        }

        f32x4 acc2[3];
        #pragma unroll
        for (int n = 0; n < 3; ++n) acc2[n] = (f32x4){0.f, 0.f, 0.f, 0.f};

        #pragma unroll
        for (int h = 0; h < 2; ++h) {
            // write z cols [64h..64h+63] (bf16) into this tile's 16 rows, bytes 0..127
            #pragma unroll
            for (int nn = 0; nn < 4; ++nn) {
                const int n = 4 * h + nn;
                #pragma unroll
                for (int i = 0; i < 4; ++i) {
                    float zv = 0.f;
                    if (n < 7) zv = relu_(acc1[n][i] + fb1v[n]);
                    const unsigned row = Rbase + 4u * lkg + (unsigned)i;
                    *(short*)&sAB[swz(row, (unsigned)((16 * nn + (int)lrow) * 2))] = f2bf(zv);
                }
            }
            // consume as fc2 A-frags for kt = 2h, 2h+1
            #pragma unroll
            for (int q = 0; q < 2; ++q) {
                const int kt = 2 * h + q;
                short8 A2 = *(const short8*)&sAB[swz(myrow, (unsigned)(q * 64) + lkg * 16u)];
                #pragma unroll
                for (int n = 0; n < 3; ++n) {
                    short8 b2 = *(const short8*)&sB2f[((n * 4 + kt) * 64 + lane) * 8];
                    acc2[n] = __builtin_amdgcn_mfma_f32_16x16x32_bf16(A2, b2, acc2[n], 0, 0, 0);
                }
            }
        }

        // out (f32) -> this tile's rows, cols 0..35
        #pragma unroll
        for (int n = 0; n < 3; ++n) {
            const unsigned col = 16u * (unsigned)n + lrow;
            #pragma unroll
            for (int i = 0; i < 4; ++i) {
                if (col < 36u) {
                    const unsigned row = Rbase + 4u * lkg + (unsigned)i;
                    *(float*)&sAB[swz(row, col * 4u)] = acc2[n][i] + fb2v[n];
                }
            }
        }
    }

    // ---- per-sample part losses from own out-row (cols 0..31) ----
    float o[32];
    #pragma unroll
    for (int b = 0; b < 8; ++b) {
        float4 v = *(const float4*)&sAB[swz((unsigned)t, (unsigned)(b * 16))];
        o[4 * b + 0] = v.x; o[4 * b + 1] = v.y; o[4 * b + 2] = v.z; o[4 * b + 3] = v.w;
    }

    float sp[5], np[5];
    {
        float dxa = o[0] - o[28], dya = o[1] - o[29];
        float dxb = o[0] - o[30], dyb = o[1] - o[31];
        float pred = 0.5f * (sqrtf(dxa*dxa + dya*dya) + sqrtf(dxb*dxb + dyb*dyb));
        float gxa = pbx[0] - o[30];
        float gt = 0.5f * (pd1[0] + sqrtf(gxa * gxa + pgy[0] * pgy[0]));
        float e = pred - gt;
        sp[0] = e * e * pvf[0]; np[0] = pvf[0];
    }
    #pragma unroll
    for (int p = 0; p < 4; ++p) {
        const int a = 2 + 3 * p, b = a + 1, cc = a + 2;
        float dxa = o[2*a] - o[2*b],  dya = o[2*a+1] - o[2*b+1];
        float dxb = o[2*b] - o[2*cc], dyb = o[2*b+1] - o[2*cc+1];
        float pred = 0.5f * (sqrtf(dxa*dxa + dya*dya) + sqrtf(dxb*dxb + dyb*dyb));
        float gxa = pbx[p + 1] - o[2 * cc];
        float gt = 0.5f * (pd1[p + 1] + sqrtf(gxa * gxa + pgy[p + 1] * pgy[p + 1]));
        float e = pred - gt;
        sp[p + 1] = e * e * pvf[p + 1]; np[p + 1] = pvf[p + 1];
    }

    __syncthreads();   // all waves' out-rows complete

    // ---- coalesced x store + miss store + elementwise kp-loss ----
    const size_t blkBase = (size_t)blockIdx.x * (NT * 36);
    const float4* cin4 = (const float4*)(cin + blkBase);
    const int4*   tm4  = (const int4*)(tmask + blkBase);
    float4*       x4   = (float4*)(xout + blkBase);
    float*        mo   = missout + blkBase;

    float s1 = 0.f, s2 = 0.f;
    #pragma unroll
    for (int i = 0; i < 9; ++i) {
        int g4 = i * NT + t;
        unsigned g = 4u * (unsigned)g4;
        unsigned row = g / 36u;
        unsigned col = g - row * 36u;          // %4 == 0 -> one 16B block
        float4 xv = *(const float4*)&sAB[swz(row, col * 4u)];
        float4 cv = cin4[g4];
        int4   mv = tm4[g4];
        x4[g4] = xv;
        mo[g + 0] = (cv.x != -1.f) ? 1.f : 0.f;
        mo[g + 1] = (cv.y != -1.f) ? 1.f : 0.f;
        mo[g + 2] = (cv.z != -1.f) ? 1.f : 0.f;
        mo[g + 3] = (cv.w != -1.f) ? 1.f : 0.f;
        float m0 = (float)mv.x, m1_ = (float)mv.y, m2_ = (float)mv.z, m3_ = (float)mv.w;
        float d0 = xv.x - cv.x, d1 = xv.y - cv.y, d2 = xv.z - cv.z, d3 = xv.w - cv.w;
        s1 += d0*d0*m0 + d1*d1*m1_ + d2*d2*m2_ + d3*d3*m3_;
        s2 += m0 + m1_ + m2_ + m3_;
    }

    // ---- block reduction of 12 scalars ----
    float rv[12] = { s1, s2, sp[0], np[0], sp[1], np[1],
                     sp[2], np[2], sp[3], np[3], sp[4], np[4] };
    #pragma unroll
    for (int v = 0; v < 12; ++v) {
        #pragma unroll
        for (int off = 32; off > 0; off >>= 1)
            rv[v] += __shfl_down(rv[v], off, 64);
    }
    const int wave = t >> 6, lane6 = t & 63;
    if (lane6 == 0) {
        #pragma unroll
        for (int v = 0; v < 12; ++v) sred[wave][v] = rv[v];
    }
    __syncthreads();
    if (t < 12) {
        float s = sred[0][t] + sred[1][t] + sred[2][t] + sred[3][t];
        partials[blockIdx.x * 12 + t] = s;
    }
}

__global__ __launch_bounds__(256) void kp_fin(const float* __restrict__ partials,
                                              float* __restrict__ total_out)
{
    __shared__ float sred[4][12];
    const int t = threadIdx.x;
    float rv[12];
    #pragma unroll
    for (int v = 0; v < 12; ++v) rv[v] = 0.f;
    for (int b = t; b < NB; b += 256) {
        #pragma unroll
        for (int v = 0; v < 12; ++v) rv[v] += partials[b * 12 + v];
    }
    #pragma unroll
    for (int v = 0; v < 12; ++v) {
        #pragma unroll
        for (int off = 32; off > 0; off >>= 1)
            rv[v] += __shfl_down(rv[v], off, 64);
    }
    const int wave = t >> 6, lane = t & 63;
    if (lane == 0) {
        #pragma unroll
        for (int v = 0; v < 12; ++v) sred[wave][v] = rv[v];
    }
    __syncthreads();
    if (t == 0) {
        float acc[12];
        #pragma unroll
        for (int v = 0; v < 12; ++v)
            acc[v] = sred[0][v] + sred[1][v] + sred[2][v] + sred[3][v];
        float total = acc[0] / acc[1];
        #pragma unroll
        for (int p = 0; p < 5; ++p) {
            float s = acc[2 + 2 * p], n = acc[3 + 2 * p];
            total += (n > 0.f) ? (s / fmaxf(n, 1.f)) : 0.f;
        }
        total_out[0] = total;
    }
}

extern "C" void kernel_launch(void* const* d_in, const int* in_sizes, int n_in,
                              void* d_out, int out_size, void* d_ws, size_t ws_size,
                              hipStream_t stream)
{
    const float* cin   = (const float*)d_in[0];
    const int*   tmask = (const int*)  d_in[1];
    const float* w1  = (const float*)d_in[2];
    const float* b1  = (const float*)d_in[3];
    const float* g1  = (const float*)d_in[4];
    const float* bt1 = (const float*)d_in[5];
    const float* m1  = (const float*)d_in[6];
    const float* v1  = (const float*)d_in[7];
    const float* w2  = (const float*)d_in[8];
    const float* b2  = (const float*)d_in[9];
    const float* g2  = (const float*)d_in[10];
    const float* bt2 = (const float*)d_in[11];
    const float* m2  = (const float*)d_in[12];
    const float* v2  = (const float*)d_in[13];
    const float* w3  = (const float*)d_in[14];
    const float* b3  = (const float*)d_in[15];
    const float* g3  = (const float*)d_in[16];
    const float* bt3 = (const float*)d_in[17];
    const float* m3  = (const float*)d_in[18];
    const float* v3  = (const float*)d_in[19];
    const float* fw1 = (const float*)d_in[20];
    const float* fb1 = (const float*)d_in[21];
    const float* fw2 = (const float*)d_in[22];
    const float* fb2 = (const float*)d_in[23];

    float* xout     = (float*)d_out;                       // [B,36]
    float* total    = (float*)d_out + (size_t)BTOT * 36;   // scalar
    float* missout  = total + 1;                           // [B,36] as f32 0/1
    float* partials = (float*)d_ws;                        // [NB,12]

    kp_fwd<<<NB, NT, 0, stream>>>(cin, tmask,
        w1, b1, g1, bt1, m1, v1,
        w2, b2, g2, bt2, m2, v2,
        w3, b3, g3, bt3, m3, v3,
        fw1, fb1, fw2, fb2,
        xout, missout, partials);

    kp_fin<<<1, 256, 0, stream>>>(partials, total);
}